// Round 5
// baseline (1222.774 us; speedup 1.0000x reference)
//
#include <hip/hip_runtime.h>
#include <hip/hip_bf16.h>
#include <math.h>

// Problem constants (from reference)
#define N_NODES 50000
#define E_EDGES 800000
#define EP (E_EDGES + N_NODES)   // 850000 edges incl. self-loops
#define IN_DIM 1280
#define HID 256
#define NHEAD 4
#define DHEAD 64
#define NEG_SLOPE 0.2f

typedef unsigned short ushort_t;
typedef __attribute__((ext_vector_type(8))) short short8;     // 8 bf16 (4 VGPRs)
typedef __attribute__((ext_vector_type(4))) float floatx4;    // MFMA acc

// truncation split: x = hi + lo + O(2^-16 x)
__device__ __forceinline__ void split_bf16(float x, ushort_t& hi, ushort_t& lo) {
  unsigned u = __float_as_uint(x);
  hi = (ushort_t)(u >> 16);
  float rem = x - __uint_as_float(u & 0xFFFF0000u);
  lo = (ushort_t)(__float_as_uint(rem) >> 16);
}

__device__ __forceinline__ void gload_lds16(const void* g, void* l) {
  __builtin_amdgcn_global_load_lds(
      (const __attribute__((address_space(1))) unsigned int*)g,
      (__attribute__((address_space(3))) unsigned int*)l, 16, 0, 0);
}

// ---------------- graph build (CSR by dst, rebuilt every call) ----------------

__global__ void hist_kernel(const int* __restrict__ ei, int* __restrict__ deg) {
  int e = blockIdx.x * blockDim.x + threadIdx.x;
  if (e >= EP) return;
  int dst = (e < E_EDGES) ? ei[E_EDGES + e] : (e - E_EDGES);
  atomicAdd(&deg[dst], 1);
}

__global__ __launch_bounds__(1024) void scan_kernel(int* __restrict__ dc, int* __restrict__ row_ptr) {
  __shared__ int wsum[16];
  int tid = threadIdx.x;
  int lane = tid & 63;
  int wid = tid >> 6;
  int running = 0;
  if (tid == 0) row_ptr[0] = 0;
  for (int base = 0; base < N_NODES; base += 1024) {
    int i = base + tid;
    int v = (i < N_NODES) ? dc[i] : 0;
    int s = v;
    #pragma unroll
    for (int off = 1; off < 64; off <<= 1) {
      int t = __shfl_up(s, off);
      if (lane >= off) s += t;
    }
    if (lane == 63) wsum[wid] = s;
    __syncthreads();
    if (wid == 0 && lane < 16) {
      int w = wsum[lane];
      #pragma unroll
      for (int off = 1; off < 16; off <<= 1) {
        int t = __shfl_up(w, off);
        if (lane >= off) w += t;
      }
      wsum[lane] = w;
    }
    __syncthreads();
    int woff = (wid > 0) ? wsum[wid - 1] : 0;
    int incl = running + woff + s;
    if (i < N_NODES) {
      row_ptr[i + 1] = incl;
      dc[i] = incl - v;
    }
    running += wsum[15];
    __syncthreads();
  }
}

__global__ void scatter_kernel(const int* __restrict__ ei, int* __restrict__ cursor,
                               int* __restrict__ csr_src, int* __restrict__ csr_eid) {
  int e = blockIdx.x * blockDim.x + threadIdx.x;
  if (e >= EP) return;
  int src, dst;
  if (e < E_EDGES) { src = ei[e]; dst = ei[E_EDGES + e]; }
  else             { src = dst = e - E_EDGES; }
  int pos = atomicAdd(&cursor[dst], 1);
  csr_src[pos] = src;
  csr_eid[pos] = e;
}

// ---------------- weight split into k-chunk-packed layout ----------------
// P[((k>>3)*NcT + colOff + n)*8 + (k&7)] = split(W[k][n]).
__global__ void wsplit_packed(const float* __restrict__ W, ushort_t* __restrict__ Ph,
                              ushort_t* __restrict__ Pl, int K, int Nc, int NcT, int colOff) {
  int idx = blockIdx.x * blockDim.x + threadIdx.x;
  if (idx >= K * Nc) return;
  int k = idx / Nc, n = idx - k * Nc;
  ushort_t hi, lo;
  split_bf16(W[idx], hi, lo);
  size_t pi = ((size_t)(k >> 3) * NcT + colOff + n) * 8 + (k & 7);
  Ph[pi] = hi;
  Pl[pi] = lo;
}

// ---------------- MFMA GEMM: C[M, 0..NcT) = A[M,K](fp32) @ W + bias ----------------
// 128x128 tile, BK=32, 4 waves (2x2, each 64x64 via 4x4 mfma_f32_16x16x32_bf16).
// Round 4 -> 5: all LDS-staged-A structures pinned at 195-210us / MfmaUtil ~20%.
// Diagnosis: A's fp32->split->LDS path couples HBM latency into the block
// barriers (split_store stalls on A, barrier propagates to all waves), and
// the A-reg issue->use gap (<1 iter) never covers ~900cyc HBM latency.
// Fix: A fragments load DIRECTLY global->registers (lane-private rows,
// contiguous 32B per lane), double-buffered vaA/vaB so issue->use gap is a
// full iteration; split to bf16 in-register at consume time. Barriers now
// protect only the B double-buffer (L2-resident, counted vmcnt(12): at each
// sub-iter top outstanding = {A(t),B(t)} 12 + just-issued {A(t+1),B(t+1)} 12).
// LDS 72KB->32KB; LDS traffic/iter 72KB->48KB. Loop unrolled x2 (nt even:
// 40 enc / 8 layers) for static va/buf indexing. No sched_barrier (m141).
__global__ __launch_bounds__(256, 2) void gemm128(const float* __restrict__ A,
                                                  const ushort_t* __restrict__ Bh,
                                                  const ushort_t* __restrict__ Bl,
                                                  const float* __restrict__ bias_l,
                                                  const float* __restrict__ bias_r,
                                                  float* __restrict__ C_l,
                                                  float* __restrict__ C_r,
                                                  int M, int K, int NcT, int Nsplit) {
  __shared__ ushort_t sBh[2][128 * 32];   // [sub_k][col] packed: elem (sub*128+col)*8
  __shared__ ushort_t sBl[2][128 * 32];

  const int tid = threadIdx.x;
  const int lane = tid & 63;
  const int w = tid >> 6;
  const int wm = w >> 1, wn = w & 1;  // 2x2 wave grid: wave tile 64x64 at (wm*64, wn*64)
  const int bm = blockIdx.x * 128;
  const int bn = blockIdx.y * 128;
  const int r = lane & 15, q = lane >> 4;

  floatx4 acc[4][4];
  #pragma unroll
  for (int i = 0; i < 4; ++i)
    #pragma unroll
    for (int j = 0; j < 4; ++j) acc[i][j] = (floatx4)(0.0f);

  // A direct-to-register: frag i covers row bm+wm*64+i*16+r, cols k0+q*8 .. +8
  const float* aAddr0;
  const float* aAddr1;
  const float* aAddr2;
  const float* aAddr3;
  {
    int r0 = bm + wm * 64 + r;
    int r1 = r0 + 16, r2 = r0 + 32, r3 = r0 + 48;
    if (r0 >= M) r0 = M - 1;   // clamp; garbage rows never stored
    if (r1 >= M) r1 = M - 1;
    if (r2 >= M) r2 = M - 1;
    if (r3 >= M) r3 = M - 1;
    aAddr0 = A + (size_t)r0 * K + q * 8;
    aAddr1 = A + (size_t)r1 * K + q * 8;
    aAddr2 = A + (size_t)r2 * K + q * 8;
    aAddr3 = A + (size_t)r3 * K + q * 8;
  }

  // B staging: entries e0=tid, e1=tid+256 of 512 x 16B per half
  const int e0 = tid, e1 = tid + 256;
  const size_t b0base = ((size_t)(e0 >> 7) * NcT + bn + (e0 & 127)) * 8;
  const size_t b1base = ((size_t)(e1 >> 7) * NcT + bn + (e1 & 127)) * 8;

  const int nt = K >> 5;   // K/32; K%64==0 for all call sites (1280, 256)

  float vaA[32], vaB[32];
  short8 ah[4], al[4];

  auto issueA = [&](float* va, int k0) {
    *(float4*)&va[0]  = *(const float4*)(aAddr0 + k0);
    *(float4*)&va[4]  = *(const float4*)(aAddr0 + k0 + 4);
    *(float4*)&va[8]  = *(const float4*)(aAddr1 + k0);
    *(float4*)&va[12] = *(const float4*)(aAddr1 + k0 + 4);
    *(float4*)&va[16] = *(const float4*)(aAddr2 + k0);
    *(float4*)&va[20] = *(const float4*)(aAddr2 + k0 + 4);
    *(float4*)&va[24] = *(const float4*)(aAddr3 + k0);
    *(float4*)&va[28] = *(const float4*)(aAddr3 + k0 + 4);
  };
  auto issueB = [&](int buf, int k0) {
    size_t kadd = (size_t)(k0 >> 3) * NcT * 8;
    gload_lds16(Bh + b0base + kadd, &sBh[buf][e0 * 8]);
    gload_lds16(Bh + b1base + kadd, &sBh[buf][e1 * 8]);
    gload_lds16(Bl + b0base + kadd, &sBl[buf][e0 * 8]);
    gload_lds16(Bl + b1base + kadd, &sBl[buf][e1 * 8]);
  };
  auto splitA = [&](const float* va) {
    #pragma unroll
    for (int i = 0; i < 4; ++i) {
      short8 hv, lv;
      #pragma unroll
      for (int u = 0; u < 8; ++u) {
        ushort_t hi, lo;
        split_bf16(va[i * 8 + u], hi, lo);
        hv[u] = (short)hi; lv[u] = (short)lo;
      }
      ah[i] = hv; al[i] = lv;
    }
  };
  auto computeTile = [&](int buf) {
    short8 bh[4], bl[4];
    #pragma unroll
    for (int j = 0; j < 4; ++j) {
      int off = (q * 128 + wn * 64 + j * 16 + r) * 8;
      bh[j] = *(const short8*)&sBh[buf][off];
      bl[j] = *(const short8*)&sBl[buf][off];
    }
    // barrier #2: my ds_reads retired -> buf may be overwritten next sub-iter.
    asm volatile("s_waitcnt lgkmcnt(0)" ::: "memory");
    __builtin_amdgcn_s_barrier();
    #pragma unroll
    for (int j = 0; j < 4; ++j)
      #pragma unroll
      for (int i = 0; i < 4; ++i) {
        acc[i][j] = __builtin_amdgcn_mfma_f32_16x16x32_bf16(ah[i], bh[j], acc[i][j], 0, 0, 0);
        acc[i][j] = __builtin_amdgcn_mfma_f32_16x16x32_bf16(ah[i], bl[j], acc[i][j], 0, 0, 0);
        acc[i][j] = __builtin_amdgcn_mfma_f32_16x16x32_bf16(al[i], bh[j], acc[i][j], 0, 0, 0);
      }
  };

  // ---- prologue: A(0)->vaA, B(0)->buf0 ----
  issueA(vaA, 0);
  issueB(0, 0);

  for (int t = 0; t < nt; t += 2) {
    // ---- even sub-iter: tile t (vaA, buf0); prefetch t+1 -> (vaB, buf1) ----
    issueA(vaB, (t + 1) << 5);            // t+1 < nt always (nt even)
    issueB(1, (t + 1) << 5);
    // drain tile t's {A 8, B 4}; leave the 12 just-issued in flight
    asm volatile("s_waitcnt vmcnt(12)" ::: "memory");
    splitA(vaA);
    __builtin_amdgcn_s_barrier();          // barrier #1: buf0 published
    computeTile(0);

    // ---- odd sub-iter: tile t+1 (vaB, buf1); prefetch t+2 -> (vaA, buf0) ----
    if (t + 2 < nt) {
      issueA(vaA, (t + 2) << 5);
      issueB(0, (t + 2) << 5);
      asm volatile("s_waitcnt vmcnt(12)" ::: "memory");
    } else {
      asm volatile("s_waitcnt vmcnt(0)" ::: "memory");
    }
    splitA(vaB);
    __builtin_amdgcn_s_barrier();          // barrier #1: buf1 published
    computeTile(1);
  }

  // epilogue: C/D layout col=lane&15, row=(lane>>4)*4+reg
  #pragma unroll
  for (int j = 0; j < 4; ++j) {
    int cg = bn + wn * 64 + j * 16 + r;
    bool sec = cg >= Nsplit;
    int cc = sec ? cg - Nsplit : cg;
    float bv = sec ? bias_r[cc] : bias_l[cc];
    float* Cb = sec ? C_r : C_l;
    #pragma unroll
    for (int i = 0; i < 4; ++i) {
      int row0 = bm + wm * 64 + i * 16 + q * 4;
      #pragma unroll
      for (int rr = 0; rr < 4; ++rr) {
        int row = row0 + rr;
        if (row < M) Cb[(size_t)row * HID + cc] = acc[i][j][rr] + bv;
      }
    }
  }
}

// ---------------- GATv2 layer: one wave per destination node, single-gather ----------------
__global__ __launch_bounds__(64) void gat_layer(const float* __restrict__ xl,
                                                const float* __restrict__ xr,
                                                float* h_inout,
                                                const float* __restrict__ att,
                                                const float* __restrict__ bias,
                                                const int* __restrict__ row_ptr,
                                                const int* __restrict__ csr_src,
                                                const int* __restrict__ csr_eid,
                                                float* __restrict__ logits_ws,
                                                float* __restrict__ alpha_out) {
  int node = blockIdx.x;
  int l = threadIdx.x;
  int hgrp = l >> 4;
  int r0 = row_ptr[node];
  int r1 = row_ptr[node + 1];

  float4 xr4 = *(const float4*)(xr + (size_t)node * HID + l * 4);
  float4 at4 = *(const float4*)(att + l * 4);

  float m = -INFINITY;
  float den = 0.f;
  float4 acc = make_float4(0.f, 0.f, 0.f, 0.f);
  for (int j = r0; j < r1; ++j) {
    int s = csr_src[j];
    float4 v = *(const float4*)(xl + (size_t)s * HID + l * 4);
    float t0 = v.x + xr4.x; t0 = (t0 > 0.f) ? t0 : NEG_SLOPE * t0;
    float t1 = v.y + xr4.y; t1 = (t1 > 0.f) ? t1 : NEG_SLOPE * t1;
    float t2 = v.z + xr4.z; t2 = (t2 > 0.f) ? t2 : NEG_SLOPE * t2;
    float t3 = v.w + xr4.w; t3 = (t3 > 0.f) ? t3 : NEG_SLOPE * t3;
    float p = t0 * at4.x + t1 * at4.y + t2 * at4.z + t3 * at4.w;
    p += __shfl_xor(p, 1);
    p += __shfl_xor(p, 2);
    p += __shfl_xor(p, 4);
    p += __shfl_xor(p, 8);
    if ((l & 15) == 0) logits_ws[(size_t)j * NHEAD + hgrp] = p;
    float m_new = fmaxf(m, p);
    float scale = __expf(m - m_new);
    float wgt = __expf(p - m_new);
    den = den * scale + wgt;
    acc.x = acc.x * scale + wgt * v.x;
    acc.y = acc.y * scale + wgt * v.y;
    acc.z = acc.z * scale + wgt * v.z;
    acc.w = acc.w * scale + wgt * v.w;
    m = m_new;
  }
  float inv_den = 1.f / (den + 1e-16f);

  float4 b4 = *(const float4*)(bias + l * 4);
  float4 h4 = *(const float4*)(h_inout + (size_t)node * HID + l * 4);
  float o0 = acc.x * inv_den + b4.x + h4.x;
  float o1 = acc.y * inv_den + b4.y + h4.y;
  float o2 = acc.z * inv_den + b4.z + h4.z;
  float o3 = acc.w * inv_den + b4.w + h4.w;
  o0 = (o0 > 0.f) ? o0 : (__expf(o0) - 1.f);
  o1 = (o1 > 0.f) ? o1 : (__expf(o1) - 1.f);
  o2 = (o2 > 0.f) ? o2 : (__expf(o2) - 1.f);
  o3 = (o3 > 0.f) ? o3 : (__expf(o3) - 1.f);
  *(float4*)(h_inout + (size_t)node * HID + l * 4) = make_float4(o0, o1, o2, o3);

  __threadfence_block();

  float mh = __shfl(m, (l & 3) * 16);
  float dh = __shfl(den, (l & 3) * 16);
  float invd = 1.f / (dh + 1e-16f);
  for (int j = r0 + (l >> 2); j < r1; j += 16) {
    float lg = logits_ws[(size_t)j * NHEAD + (l & 3)];
    alpha_out[(size_t)csr_eid[j] * NHEAD + (l & 3)] = __expf(lg - mh) * invd;
  }
}

// ---------------- classifier ----------------
__global__ __launch_bounds__(64) void clf_kernel(const float* __restrict__ h,
                                                 const float* __restrict__ clf_W,
                                                 const float* __restrict__ clf_b,
                                                 float* __restrict__ preds) {
  int n = blockIdx.x;
  int l = threadIdx.x;
  float4 v = *(const float4*)(h + (size_t)n * HID + l * 4);
  float4 w = *(const float4*)(clf_W + l * 4);
  float s = v.x * w.x + v.y * w.y + v.z * w.z + v.w * w.w;
  s += __shfl_xor(s, 1);
  s += __shfl_xor(s, 2);
  s += __shfl_xor(s, 4);
  s += __shfl_xor(s, 8);
  s += __shfl_xor(s, 16);
  s += __shfl_xor(s, 32);
  if (l == 0) preds[n] = s + clf_b[0];
}

// ---------------- launcher ----------------
static inline char* carve(char*& p, size_t bytes) {
  char* ret = p;
  p += (bytes + 255) & ~(size_t)255;
  return ret;
}

extern "C" void kernel_launch(void* const* d_in, const int* in_sizes, int n_in,
                              void* d_out, int out_size, void* d_ws, size_t ws_size,
                              hipStream_t stream) {
  const float* x     = (const float*)d_in[0];
  const int*   ei    = (const int*)d_in[1];
  const float* enc_W = (const float*)d_in[2];
  const float* enc_b = (const float*)d_in[3];
  const float* Wl0   = (const float*)d_in[4];
  const float* bl0   = (const float*)d_in[5];
  const float* Wr0   = (const float*)d_in[6];
  const float* br0   = (const float*)d_in[7];
  const float* att0  = (const float*)d_in[8];
  const float* bias0 = (const float*)d_in[9];
  const float* Wl1   = (const float*)d_in[10];
  const float* bl1   = (const float*)d_in[11];
  const float* Wr1   = (const float*)d_in[12];
  const float* br1   = (const float*)d_in[13];
  const float* att1  = (const float*)d_in[14];
  const float* bias1 = (const float*)d_in[15];
  const float* clf_W = (const float*)d_in[16];
  const float* clf_b = (const float*)d_in[17];

  float* preds  = (float*)d_out;
  float* alpha0 = preds + N_NODES;
  float* alpha1 = alpha0 + (size_t)EP * NHEAD;

  char* p = (char*)d_ws;
  float* h      = (float*)carve(p, (size_t)N_NODES * HID * 4);
  float* xl     = (float*)carve(p, (size_t)N_NODES * HID * 4);
  float* xr     = (float*)carve(p, (size_t)N_NODES * HID * 4);
  float* logits = (float*)carve(p, (size_t)EP * NHEAD * 4);
  int* row_ptr  = (int*)carve(p, (size_t)(N_NODES + 1) * 4);
  int* cursor   = (int*)carve(p, (size_t)N_NODES * 4);
  int* csr_src  = (int*)carve(p, (size_t)EP * 4);
  int* csr_eid  = (int*)carve(p, (size_t)EP * 4);
  ushort_t* encPh = (ushort_t*)carve(p, (size_t)IN_DIM * HID * 2);
  ushort_t* encPl = (ushort_t*)carve(p, (size_t)IN_DIM * HID * 2);
  ushort_t* P0h   = (ushort_t*)carve(p, (size_t)HID * 512 * 2);
  ushort_t* P0l   = (ushort_t*)carve(p, (size_t)HID * 512 * 2);
  ushort_t* P1h   = (ushort_t*)carve(p, (size_t)HID * 512 * 2);
  ushort_t* P1l   = (ushort_t*)carve(p, (size_t)HID * 512 * 2);

  // --- CSR build ---
  hipMemsetAsync(cursor, 0, N_NODES * sizeof(int), stream);
  int eb = 256, eg = (EP + eb - 1) / eb;
  hist_kernel<<<eg, eb, 0, stream>>>(ei, cursor);
  scan_kernel<<<1, 1024, 0, stream>>>(cursor, row_ptr);
  scatter_kernel<<<eg, eb, 0, stream>>>(ei, cursor, csr_src, csr_eid);

  // --- weight preprocessing: packed split. Layer weights concat [Wl | Wr] along cols ---
  int wt = 256;
  wsplit_packed<<<(IN_DIM * HID + wt - 1) / wt, wt, 0, stream>>>(enc_W, encPh, encPl, IN_DIM, HID, HID, 0);
  wsplit_packed<<<(HID * HID + wt - 1) / wt, wt, 0, stream>>>(Wl0, P0h, P0l, HID, HID, 512, 0);
  wsplit_packed<<<(HID * HID + wt - 1) / wt, wt, 0, stream>>>(Wr0, P0h, P0l, HID, HID, 512, 256);
  wsplit_packed<<<(HID * HID + wt - 1) / wt, wt, 0, stream>>>(Wl1, P1h, P1l, HID, HID, 512, 0);
  wsplit_packed<<<(HID * HID + wt - 1) / wt, wt, 0, stream>>>(Wr1, P1h, P1l, HID, HID, 512, 256);

  const int MB = (N_NODES + 127) / 128;   // 391
  dim3 bGemm(256);

  // encoder: h = x @ enc_W + enc_b   (NcT=256, all cols -> h)
  gemm128<<<dim3(MB, 2), bGemm, 0, stream>>>(x, encPh, encPl, enc_b, enc_b, h, h,
                                             N_NODES, IN_DIM, HID, HID);

  // layer 0: fused xl|xr = h @ [Wl0|Wr0]
  gemm128<<<dim3(MB, 4), bGemm, 0, stream>>>(h, P0h, P0l, bl0, br0, xl, xr,
                                             N_NODES, HID, 512, HID);
  gat_layer<<<N_NODES, 64, 0, stream>>>(xl, xr, h, att0, bias0, row_ptr, csr_src, csr_eid, logits, alpha0);

  // layer 1
  gemm128<<<dim3(MB, 4), bGemm, 0, stream>>>(h, P1h, P1l, bl1, br1, xl, xr,
                                             N_NODES, HID, 512, HID);
  gat_layer<<<N_NODES, 64, 0, stream>>>(xl, xr, h, att1, bias1, row_ptr, csr_src, csr_eid, logits, alpha1);

  // classifier
  clf_kernel<<<N_NODES, 64, 0, stream>>>(h, clf_W, clf_b, preds);
}

// Round 6
// 1085.286 us; speedup vs baseline: 1.1267x; 1.1267x over previous
//
#include <hip/hip_runtime.h>
#include <hip/hip_bf16.h>
#include <math.h>

// Problem constants (from reference)
#define N_NODES 50000
#define E_EDGES 800000
#define EP (E_EDGES + N_NODES)   // 850000 edges incl. self-loops
#define IN_DIM 1280
#define HID 256
#define NHEAD 4
#define DHEAD 64
#define NEG_SLOPE 0.2f

typedef unsigned short ushort_t;
typedef __attribute__((ext_vector_type(8))) short short8;     // 8 bf16 (4 VGPRs)
typedef __attribute__((ext_vector_type(4))) float floatx4;    // MFMA acc

// truncation split: x = hi + lo + O(2^-16 x)
__device__ __forceinline__ void split_bf16(float x, ushort_t& hi, ushort_t& lo) {
  unsigned u = __float_as_uint(x);
  hi = (ushort_t)(u >> 16);
  float rem = x - __uint_as_float(u & 0xFFFF0000u);
  lo = (ushort_t)(__float_as_uint(rem) >> 16);
}

__device__ __forceinline__ void gload_lds16(const void* g, void* l) {
  __builtin_amdgcn_global_load_lds(
      (const __attribute__((address_space(1))) unsigned int*)g,
      (__attribute__((address_space(3))) unsigned int*)l, 16, 0, 0);
}

// ---------------- graph build (CSR by dst, rebuilt every call) ----------------

__global__ void hist_kernel(const int* __restrict__ ei, int* __restrict__ deg) {
  int e = blockIdx.x * blockDim.x + threadIdx.x;
  if (e >= EP) return;
  int dst = (e < E_EDGES) ? ei[E_EDGES + e] : (e - E_EDGES);
  atomicAdd(&deg[dst], 1);
}

__global__ __launch_bounds__(1024) void scan_kernel(int* __restrict__ dc, int* __restrict__ row_ptr) {
  __shared__ int wsum[16];
  int tid = threadIdx.x;
  int lane = tid & 63;
  int wid = tid >> 6;
  int running = 0;
  if (tid == 0) row_ptr[0] = 0;
  for (int base = 0; base < N_NODES; base += 1024) {
    int i = base + tid;
    int v = (i < N_NODES) ? dc[i] : 0;
    int s = v;
    #pragma unroll
    for (int off = 1; off < 64; off <<= 1) {
      int t = __shfl_up(s, off);
      if (lane >= off) s += t;
    }
    if (lane == 63) wsum[wid] = s;
    __syncthreads();
    if (wid == 0 && lane < 16) {
      int w = wsum[lane];
      #pragma unroll
      for (int off = 1; off < 16; off <<= 1) {
        int t = __shfl_up(w, off);
        if (lane >= off) w += t;
      }
      wsum[lane] = w;
    }
    __syncthreads();
    int woff = (wid > 0) ? wsum[wid - 1] : 0;
    int incl = running + woff + s;
    if (i < N_NODES) {
      row_ptr[i + 1] = incl;
      dc[i] = incl - v;
    }
    running += wsum[15];
    __syncthreads();
  }
}

__global__ void scatter_kernel(const int* __restrict__ ei, int* __restrict__ cursor,
                               int* __restrict__ csr_src, int* __restrict__ csr_eid) {
  int e = blockIdx.x * blockDim.x + threadIdx.x;
  if (e >= EP) return;
  int src, dst;
  if (e < E_EDGES) { src = ei[e]; dst = ei[E_EDGES + e]; }
  else             { src = dst = e - E_EDGES; }
  int pos = atomicAdd(&cursor[dst], 1);
  csr_src[pos] = src;
  csr_eid[pos] = e;
}

// ---------------- weight split into k-chunk-packed layout ----------------
// P[((k>>3)*NcT + colOff + n)*8 + (k&7)] = split(W[k][n]).
__global__ void wsplit_packed(const float* __restrict__ W, ushort_t* __restrict__ Ph,
                              ushort_t* __restrict__ Pl, int K, int Nc, int NcT, int colOff) {
  int idx = blockIdx.x * blockDim.x + threadIdx.x;
  if (idx >= K * Nc) return;
  int k = idx / Nc, n = idx - k * Nc;
  ushort_t hi, lo;
  split_bf16(W[idx], hi, lo);
  size_t pi = ((size_t)(k >> 3) * NcT + colOff + n) * 8 + (k & 7);
  Ph[pi] = hi;
  Pl[pi] = lo;
}

// split 16 floats -> hi/lo bf16x8 pairs -> LDS
__device__ __forceinline__ void split_store16(const float* va, ushort_t* dAh,
                                              ushort_t* dAl, int awoff) {
  #pragma unroll
  for (int hh = 0; hh < 2; ++hh) {
    short8 hv, lv;
    #pragma unroll
    for (int i = 0; i < 8; ++i) {
      ushort_t hi, lo;
      split_bf16(va[hh * 8 + i], hi, lo);
      hv[i] = (short)hi; lv[i] = (short)lo;
    }
    *(short8*)&dAh[awoff + hh * 8] = hv;
    *(short8*)&dAl[awoff + hh * 8] = lv;
  }
}

// ---------------- MFMA GEMM: C[M, 0..NcT) = A[M,K](fp32) @ W + bias ----------------
// 128x128 tile, BK=32, 4 waves (2x2, each 64x64), round-3 structure (best
// measured 193us): dbuf LDS + 1-iter reg prefetch + __syncthreads.
// Round 5 -> 6: five micro-structure variants all pinned at 195-265us =>
// the encoder GEMM's operating point is structural; attack launch-level
// waste instead. The LAYER GEMMs (grid 391x4, x-major) re-fetch A=h once
// per column-panel (~205MB vs 51MB). Fix: 1-D swizzled grid co-locating
// the P col-panels of each row-panel on ONE XCD (id = (R&7) + 8*(P*(R>>3)+c))
// so the A row-panel is fetched into that XCD's L2 once and hit by its P
// sibling blocks (T1 mechanism: neighbor blocks share operand panels).
__global__ __launch_bounds__(256, 2) void gemm128(const float* __restrict__ A,
                                                  const ushort_t* __restrict__ Bh,
                                                  const ushort_t* __restrict__ Bl,
                                                  const float* __restrict__ bias_l,
                                                  const float* __restrict__ bias_r,
                                                  float* __restrict__ C_l,
                                                  float* __restrict__ C_r,
                                                  int M, int K, int NcT, int Nsplit) {
  __shared__ ushort_t sAh[2][128 * 40];   // padded: row stride 40 bf16 (80 B)
  __shared__ ushort_t sAl[2][128 * 40];
  __shared__ ushort_t sBh[2][128 * 32];   // [sub_k][col] packed: elem (sub*128+col)*8
  __shared__ ushort_t sBl[2][128 * 32];

  // swizzled 1-D grid decode: co-locate all P col-panels of a row-panel on one XCD
  const int P = NcT >> 7;                  // 2 (enc) or 4 (layers)
  const int plog = (P == 2) ? 1 : 2;
  const int id = blockIdx.x;
  const int xcd = id & 7;
  const int kk = id >> 3;
  const int cpan = kk & (P - 1);
  const int Rhi = kk >> plog;
  const int R = (Rhi << 3) + xcd;          // row panel
  const int MBp = (M + 127) >> 7;
  if (R >= MBp) return;                    // idle pad block (whole block exits)

  const int tid = threadIdx.x;
  const int lane = tid & 63;
  const int w = tid >> 6;
  const int wm = w >> 1, wn = w & 1;  // 2x2 wave grid: wave tile 64x64 at (wm*64, wn*64)
  const int bm = R * 128;
  const int bn = cpan * 128;
  const int r = lane & 15, q = lane >> 4;

  floatx4 acc[4][4];
  #pragma unroll
  for (int i = 0; i < 4; ++i)
    #pragma unroll
    for (int j = 0; j < 4; ++j) acc[i][j] = (floatx4)(0.0f);

  // A staging: thread -> row=tid>>1 (128 rows), chunk=tid&1 (16 floats each)
  const int arow = tid >> 1, achunk = tid & 1;
  int ag = bm + arow; if (ag >= M) ag = M - 1;   // clamp; garbage rows never stored
  const float* aptr = A + (size_t)ag * K + achunk * 16;
  const int awoff = arow * 40 + achunk * 16;

  // B staging: entries e0=tid, e1=tid+256 of 512 x 16B per half
  const int e0 = tid, e1 = tid + 256;
  const size_t b0base = ((size_t)(e0 >> 7) * NcT + bn + (e0 & 127)) * 8;
  const size_t b1base = ((size_t)(e1 >> 7) * NcT + bn + (e1 & 127)) * 8;

  const int nt = K >> 5;   // K / 32

  // ---- prologue: fill buffer 0 with tile 0 ----
  {
    gload_lds16(Bh + b0base, &sBh[0][e0 * 8]);
    gload_lds16(Bh + b1base, &sBh[0][e1 * 8]);
    gload_lds16(Bl + b0base, &sBl[0][e0 * 8]);
    gload_lds16(Bl + b1base, &sBl[0][e1 * 8]);
    float va[16];
    *(float4*)&va[0]  = *(const float4*)(aptr + 0);
    *(float4*)&va[4]  = *(const float4*)(aptr + 4);
    *(float4*)&va[8]  = *(const float4*)(aptr + 8);
    *(float4*)&va[12] = *(const float4*)(aptr + 12);
    split_store16(va, sAh[0], sAl[0], awoff);
  }
  __syncthreads();

  int cur = 0;
  for (int t = 0; t < nt; ++t) {
    const bool has_next = (t + 1 < nt);
    float va[16];
    if (has_next) {
      const int k0n = (t + 1) << 5;
      // issue next A loads to regs (HBM latency hides under MFMA below)
      *(float4*)&va[0]  = *(const float4*)(aptr + k0n + 0);
      *(float4*)&va[4]  = *(const float4*)(aptr + k0n + 4);
      *(float4*)&va[8]  = *(const float4*)(aptr + k0n + 8);
      *(float4*)&va[12] = *(const float4*)(aptr + k0n + 12);
      // issue next B async global->LDS into buf^1
      size_t kadd = (size_t)(k0n >> 3) * NcT * 8;
      gload_lds16(Bh + b0base + kadd, &sBh[cur ^ 1][e0 * 8]);
      gload_lds16(Bh + b1base + kadd, &sBh[cur ^ 1][e1 * 8]);
      gload_lds16(Bl + b0base + kadd, &sBl[cur ^ 1][e0 * 8]);
      gload_lds16(Bl + b1base + kadd, &sBl[cur ^ 1][e1 * 8]);
    }

    // compute current tile from buf[cur]
    short8 ah[4], al[4];
    #pragma unroll
    for (int i = 0; i < 4; ++i) {
      int off = (wm * 64 + i * 16 + r) * 40 + q * 8;
      ah[i] = *(const short8*)&sAh[cur][off];
      al[i] = *(const short8*)&sAl[cur][off];
    }
    #pragma unroll
    for (int j = 0; j < 4; ++j) {
      int off = (q * 128 + wn * 64 + j * 16 + r) * 8;
      short8 bh = *(const short8*)&sBh[cur][off];
      short8 bl = *(const short8*)&sBl[cur][off];
      #pragma unroll
      for (int i = 0; i < 4; ++i) {
        acc[i][j] = __builtin_amdgcn_mfma_f32_16x16x32_bf16(ah[i], bh, acc[i][j], 0, 0, 0);
        acc[i][j] = __builtin_amdgcn_mfma_f32_16x16x32_bf16(ah[i], bl, acc[i][j], 0, 0, 0);
        acc[i][j] = __builtin_amdgcn_mfma_f32_16x16x32_bf16(al[i], bh, acc[i][j], 0, 0, 0);
      }
    }

    // split prefetched A into buf^1 (waits only on this iteration's A loads)
    if (has_next) split_store16(va, sAh[cur ^ 1], sAl[cur ^ 1], awoff);

    // one drain + barrier per tile
    __syncthreads();
    cur ^= 1;
  }

  // epilogue: C/D layout col=lane&15, row=(lane>>4)*4+reg
  #pragma unroll
  for (int j = 0; j < 4; ++j) {
    int cg = bn + wn * 64 + j * 16 + r;
    bool sec = cg >= Nsplit;
    int cc = sec ? cg - Nsplit : cg;
    float bv = sec ? bias_r[cc] : bias_l[cc];
    float* Cb = sec ? C_r : C_l;
    #pragma unroll
    for (int i = 0; i < 4; ++i) {
      int row0 = bm + wm * 64 + i * 16 + q * 4;
      #pragma unroll
      for (int rr = 0; rr < 4; ++rr) {
        int row = row0 + rr;
        if (row < M) Cb[(size_t)row * HID + cc] = acc[i][j][rr] + bv;
      }
    }
  }
}

// ---------------- GATv2 layer: one wave per destination node, 4 nodes/block ----------------
__global__ __launch_bounds__(256) void gat_layer(const float* __restrict__ xl,
                                                 const float* __restrict__ xr,
                                                 float* h_inout,
                                                 const float* __restrict__ att,
                                                 const float* __restrict__ bias,
                                                 const int* __restrict__ row_ptr,
                                                 const int* __restrict__ csr_src,
                                                 const int* __restrict__ csr_eid,
                                                 float* __restrict__ logits_ws,
                                                 float* __restrict__ alpha_out) {
  int node = blockIdx.x * 4 + (threadIdx.x >> 6);   // N_NODES % 4 == 0
  int l = threadIdx.x & 63;
  int hgrp = l >> 4;
  int r0 = row_ptr[node];
  int r1 = row_ptr[node + 1];

  float4 xr4 = *(const float4*)(xr + (size_t)node * HID + l * 4);
  float4 at4 = *(const float4*)(att + l * 4);

  float m = -INFINITY;
  float den = 0.f;
  float4 acc = make_float4(0.f, 0.f, 0.f, 0.f);
  for (int j = r0; j < r1; ++j) {
    int s = csr_src[j];
    float4 v = *(const float4*)(xl + (size_t)s * HID + l * 4);
    float t0 = v.x + xr4.x; t0 = (t0 > 0.f) ? t0 : NEG_SLOPE * t0;
    float t1 = v.y + xr4.y; t1 = (t1 > 0.f) ? t1 : NEG_SLOPE * t1;
    float t2 = v.z + xr4.z; t2 = (t2 > 0.f) ? t2 : NEG_SLOPE * t2;
    float t3 = v.w + xr4.w; t3 = (t3 > 0.f) ? t3 : NEG_SLOPE * t3;
    float p = t0 * at4.x + t1 * at4.y + t2 * at4.z + t3 * at4.w;
    p += __shfl_xor(p, 1);
    p += __shfl_xor(p, 2);
    p += __shfl_xor(p, 4);
    p += __shfl_xor(p, 8);
    if ((l & 15) == 0) logits_ws[(size_t)j * NHEAD + hgrp] = p;
    float m_new = fmaxf(m, p);
    float scale = __expf(m - m_new);
    float wgt = __expf(p - m_new);
    den = den * scale + wgt;
    acc.x = acc.x * scale + wgt * v.x;
    acc.y = acc.y * scale + wgt * v.y;
    acc.z = acc.z * scale + wgt * v.z;
    acc.w = acc.w * scale + wgt * v.w;
    m = m_new;
  }
  float inv_den = 1.f / (den + 1e-16f);

  float4 b4 = *(const float4*)(bias + l * 4);
  float4 h4 = *(const float4*)(h_inout + (size_t)node * HID + l * 4);
  float o0 = acc.x * inv_den + b4.x + h4.x;
  float o1 = acc.y * inv_den + b4.y + h4.y;
  float o2 = acc.z * inv_den + b4.z + h4.z;
  float o3 = acc.w * inv_den + b4.w + h4.w;
  o0 = (o0 > 0.f) ? o0 : (__expf(o0) - 1.f);
  o1 = (o1 > 0.f) ? o1 : (__expf(o1) - 1.f);
  o2 = (o2 > 0.f) ? o2 : (__expf(o2) - 1.f);
  o3 = (o3 > 0.f) ? o3 : (__expf(o3) - 1.f);
  *(float4*)(h_inout + (size_t)node * HID + l * 4) = make_float4(o0, o1, o2, o3);

  __threadfence_block();

  float mh = __shfl(m, (l & 3) * 16);
  float dh = __shfl(den, (l & 3) * 16);
  float invd = 1.f / (dh + 1e-16f);
  for (int j = r0 + (l >> 2); j < r1; j += 16) {
    float lg = logits_ws[(size_t)j * NHEAD + (l & 3)];
    alpha_out[(size_t)csr_eid[j] * NHEAD + (l & 3)] = __expf(lg - mh) * invd;
  }
}

// ---------------- classifier ----------------
__global__ __launch_bounds__(64) void clf_kernel(const float* __restrict__ h,
                                                 const float* __restrict__ clf_W,
                                                 const float* __restrict__ clf_b,
                                                 float* __restrict__ preds) {
  int n = blockIdx.x;
  int l = threadIdx.x;
  float4 v = *(const float4*)(h + (size_t)n * HID + l * 4);
  float4 w = *(const float4*)(clf_W + l * 4);
  float s = v.x * w.x + v.y * w.y + v.z * w.z + v.w * w.w;
  s += __shfl_xor(s, 1);
  s += __shfl_xor(s, 2);
  s += __shfl_xor(s, 4);
  s += __shfl_xor(s, 8);
  s += __shfl_xor(s, 16);
  s += __shfl_xor(s, 32);
  if (l == 0) preds[n] = s + clf_b[0];
}

// ---------------- launcher ----------------
static inline char* carve(char*& p, size_t bytes) {
  char* ret = p;
  p += (bytes + 255) & ~(size_t)255;
  return ret;
}

extern "C" void kernel_launch(void* const* d_in, const int* in_sizes, int n_in,
                              void* d_out, int out_size, void* d_ws, size_t ws_size,
                              hipStream_t stream) {
  const float* x     = (const float*)d_in[0];
  const int*   ei    = (const int*)d_in[1];
  const float* enc_W = (const float*)d_in[2];
  const float* enc_b = (const float*)d_in[3];
  const float* Wl0   = (const float*)d_in[4];
  const float* bl0   = (const float*)d_in[5];
  const float* Wr0   = (const float*)d_in[6];
  const float* br0   = (const float*)d_in[7];
  const float* att0  = (const float*)d_in[8];
  const float* bias0 = (const float*)d_in[9];
  const float* Wl1   = (const float*)d_in[10];
  const float* bl1   = (const float*)d_in[11];
  const float* Wr1   = (const float*)d_in[12];
  const float* br1   = (const float*)d_in[13];
  const float* att1  = (const float*)d_in[14];
  const float* bias1 = (const float*)d_in[15];
  const float* clf_W = (const float*)d_in[16];
  const float* clf_b = (const float*)d_in[17];

  float* preds  = (float*)d_out;
  float* alpha0 = preds + N_NODES;
  float* alpha1 = alpha0 + (size_t)EP * NHEAD;

  char* p = (char*)d_ws;
  float* h      = (float*)carve(p, (size_t)N_NODES * HID * 4);
  float* xl     = (float*)carve(p, (size_t)N_NODES * HID * 4);
  float* xr     = (float*)carve(p, (size_t)N_NODES * HID * 4);
  float* logits = (float*)carve(p, (size_t)EP * NHEAD * 4);
  int* row_ptr  = (int*)carve(p, (size_t)(N_NODES + 1) * 4);
  int* cursor   = (int*)carve(p, (size_t)N_NODES * 4);
  int* csr_src  = (int*)carve(p, (size_t)EP * 4);
  int* csr_eid  = (int*)carve(p, (size_t)EP * 4);
  ushort_t* encPh = (ushort_t*)carve(p, (size_t)IN_DIM * HID * 2);
  ushort_t* encPl = (ushort_t*)carve(p, (size_t)IN_DIM * HID * 2);
  ushort_t* P0h   = (ushort_t*)carve(p, (size_t)HID * 512 * 2);
  ushort_t* P0l   = (ushort_t*)carve(p, (size_t)HID * 512 * 2);
  ushort_t* P1h   = (ushort_t*)carve(p, (size_t)HID * 512 * 2);
  ushort_t* P1l   = (ushort_t*)carve(p, (size_t)HID * 512 * 2);

  // --- CSR build ---
  hipMemsetAsync(cursor, 0, N_NODES * sizeof(int), stream);
  int eb = 256, eg = (EP + eb - 1) / eb;
  hist_kernel<<<eg, eb, 0, stream>>>(ei, cursor);
  scan_kernel<<<1, 1024, 0, stream>>>(cursor, row_ptr);
  scatter_kernel<<<eg, eb, 0, stream>>>(ei, cursor, csr_src, csr_eid);

  // --- weight preprocessing: packed split. Layer weights concat [Wl | Wr] along cols ---
  int wt = 256;
  wsplit_packed<<<(IN_DIM * HID + wt - 1) / wt, wt, 0, stream>>>(enc_W, encPh, encPl, IN_DIM, HID, HID, 0);
  wsplit_packed<<<(HID * HID + wt - 1) / wt, wt, 0, stream>>>(Wl0, P0h, P0l, HID, HID, 512, 0);
  wsplit_packed<<<(HID * HID + wt - 1) / wt, wt, 0, stream>>>(Wr0, P0h, P0l, HID, HID, 512, 256);
  wsplit_packed<<<(HID * HID + wt - 1) / wt, wt, 0, stream>>>(Wl1, P1h, P1l, HID, HID, 512, 0);
  wsplit_packed<<<(HID * HID + wt - 1) / wt, wt, 0, stream>>>(Wr1, P1h, P1l, HID, HID, 512, 256);

  const int MB = (N_NODES + 127) / 128;      // 391 row-panels
  const int R8 = (MB + 7) / 8;               // 49
  dim3 bGemm(256);

  // swizzled 1-D grids: 8 XCD slots x P col-panels x R8 row-groups
  // encoder: h = x @ enc_W + enc_b   (NcT=256 -> P=2)
  gemm128<<<dim3(8 * 2 * R8), bGemm, 0, stream>>>(x, encPh, encPl, enc_b, enc_b, h, h,
                                                  N_NODES, IN_DIM, HID, HID);

  // layer 0: fused xl|xr = h @ [Wl0|Wr0]   (NcT=512 -> P=4)
  gemm128<<<dim3(8 * 4 * R8), bGemm, 0, stream>>>(h, P0h, P0l, bl0, br0, xl, xr,
                                                  N_NODES, HID, 512, HID);
  gat_layer<<<N_NODES / 4, 256, 0, stream>>>(xl, xr, h, att0, bias0, row_ptr, csr_src, csr_eid, logits, alpha0);

  // layer 1
  gemm128<<<dim3(8 * 4 * R8), bGemm, 0, stream>>>(h, P1h, P1l, bl1, br1, xl, xr,
                                                  N_NODES, HID, 512, HID);
  gat_layer<<<N_NODES / 4, 256, 0, stream>>>(xl, xr, h, att1, bias1, row_ptr, csr_src, csr_eid, logits, alpha1);

  // classifier
  clf_kernel<<<N_NODES, 64, 0, stream>>>(h, clf_W, clf_b, preds);
}

// Round 7
// 1055.045 us; speedup vs baseline: 1.1590x; 1.0287x over previous
//
#include <hip/hip_runtime.h>
#include <hip/hip_bf16.h>
#include <math.h>

// Problem constants (from reference)
#define N_NODES 50000
#define E_EDGES 800000
#define EP (E_EDGES + N_NODES)   // 850000 edges incl. self-loops
#define IN_DIM 1280
#define HID 256
#define NHEAD 4
#define DHEAD 64
#define NEG_SLOPE 0.2f

typedef unsigned short ushort_t;
typedef __attribute__((ext_vector_type(8))) short short8;     // 8 bf16 (4 VGPRs)
typedef __attribute__((ext_vector_type(4))) float floatx4;    // MFMA acc

// truncation split: x = hi + lo + O(2^-16 x)
__device__ __forceinline__ void split_bf16(float x, ushort_t& hi, ushort_t& lo) {
  unsigned u = __float_as_uint(x);
  hi = (ushort_t)(u >> 16);
  float rem = x - __uint_as_float(u & 0xFFFF0000u);
  lo = (ushort_t)(__float_as_uint(rem) >> 16);
}

__device__ __forceinline__ void gload_lds16(const void* g, void* l) {
  __builtin_amdgcn_global_load_lds(
      (const __attribute__((address_space(1))) unsigned int*)g,
      (__attribute__((address_space(3))) unsigned int*)l, 16, 0, 0);
}

// ---------------- graph build (CSR by dst, rebuilt every call) ----------------

__global__ void hist_kernel(const int* __restrict__ ei, int* __restrict__ deg) {
  int e = blockIdx.x * blockDim.x + threadIdx.x;
  if (e >= EP) return;
  int dst = (e < E_EDGES) ? ei[E_EDGES + e] : (e - E_EDGES);
  atomicAdd(&deg[dst], 1);
}

__global__ __launch_bounds__(1024) void scan_kernel(int* __restrict__ dc, int* __restrict__ row_ptr) {
  __shared__ int wsum[16];
  int tid = threadIdx.x;
  int lane = tid & 63;
  int wid = tid >> 6;
  int running = 0;
  if (tid == 0) row_ptr[0] = 0;
  for (int base = 0; base < N_NODES; base += 1024) {
    int i = base + tid;
    int v = (i < N_NODES) ? dc[i] : 0;
    int s = v;
    #pragma unroll
    for (int off = 1; off < 64; off <<= 1) {
      int t = __shfl_up(s, off);
      if (lane >= off) s += t;
    }
    if (lane == 63) wsum[wid] = s;
    __syncthreads();
    if (wid == 0 && lane < 16) {
      int w = wsum[lane];
      #pragma unroll
      for (int off = 1; off < 16; off <<= 1) {
        int t = __shfl_up(w, off);
        if (lane >= off) w += t;
      }
      wsum[lane] = w;
    }
    __syncthreads();
    int woff = (wid > 0) ? wsum[wid - 1] : 0;
    int incl = running + woff + s;
    if (i < N_NODES) {
      row_ptr[i + 1] = incl;
      dc[i] = incl - v;
    }
    running += wsum[15];
    __syncthreads();
  }
}

__global__ void scatter_kernel(const int* __restrict__ ei, int* __restrict__ cursor,
                               int* __restrict__ csr_src, int* __restrict__ csr_eid) {
  int e = blockIdx.x * blockDim.x + threadIdx.x;
  if (e >= EP) return;
  int src, dst;
  if (e < E_EDGES) { src = ei[e]; dst = ei[E_EDGES + e]; }
  else             { src = dst = e - E_EDGES; }
  int pos = atomicAdd(&cursor[dst], 1);
  csr_src[pos] = src;
  csr_eid[pos] = e;
}

// ---------------- weight split into k-chunk-packed layout (all 5 W fused) ----------------
// P[((k>>3)*NcT + colOff + n)*8 + (k&7)] = split(W[k][n]).  Nc==256 for every matrix.
#define ENC_ELEMS (IN_DIM * HID)   // 327680
#define LYR_ELEMS (HID * HID)      // 65536
__global__ void wsplit_all(const float* __restrict__ enc_W,
                           const float* __restrict__ Wl0, const float* __restrict__ Wr0,
                           const float* __restrict__ Wl1, const float* __restrict__ Wr1,
                           ushort_t* __restrict__ encPh, ushort_t* __restrict__ encPl,
                           ushort_t* __restrict__ P0h, ushort_t* __restrict__ P0l,
                           ushort_t* __restrict__ P1h, ushort_t* __restrict__ P1l) {
  int idx = blockIdx.x * blockDim.x + threadIdx.x;
  const float* W; ushort_t *Ph, *Pl; int NcT, colOff, r;
  if (idx < ENC_ELEMS) {
    W = enc_W; Ph = encPh; Pl = encPl; NcT = HID; colOff = 0; r = idx;
  } else {
    int q = idx - ENC_ELEMS;
    int mId = q >> 16;               // 0..3 -> Wl0,Wr0,Wl1,Wr1
    if (mId >= 4) return;
    r = q & 0xFFFF;
    W  = (mId == 0) ? Wl0 : (mId == 1) ? Wr0 : (mId == 2) ? Wl1 : Wr1;
    Ph = (mId < 2) ? P0h : P1h;
    Pl = (mId < 2) ? P0l : P1l;
    NcT = 512; colOff = (mId & 1) * 256;
  }
  int k = r >> 8, n = r & 255;
  ushort_t hi, lo;
  split_bf16(W[r], hi, lo);
  size_t pi = ((size_t)(k >> 3) * NcT + colOff + n) * 8 + (k & 7);
  Ph[pi] = hi;
  Pl[pi] = lo;
}

// split 16 floats -> hi/lo bf16x8 pairs -> LDS
__device__ __forceinline__ void split_store16(const float* va, ushort_t* dAh,
                                              ushort_t* dAl, int awoff) {
  #pragma unroll
  for (int hh = 0; hh < 2; ++hh) {
    short8 hv, lv;
    #pragma unroll
    for (int i = 0; i < 8; ++i) {
      ushort_t hi, lo;
      split_bf16(va[hh * 8 + i], hi, lo);
      hv[i] = (short)hi; lv[i] = (short)lo;
    }
    *(short8*)&dAh[awoff + hh * 8] = hv;
    *(short8*)&dAl[awoff + hh * 8] = lv;
  }
}

// ---------------- MFMA GEMM: C[M, 0..NcT) = A[M,K](fp32) @ W + bias ----------------
// 128x128 tile, BK=32, 4 waves (2x2, each 64x64), round-3 structure (best measured):
// dbuf LDS + 1-iter reg prefetch + __syncthreads. XCD-swizzled 1-D grid (round 6):
// co-locates the P col-panels of each row-panel on one XCD (halved encoder FETCH).
// Micro-structure is at its operating point (rounds 0-5: LDS traffic, bank
// conflicts, occupancy, buffering depth, vmcnt discipline all null at ~190us).
__global__ __launch_bounds__(256, 2) void gemm128(const float* __restrict__ A,
                                                  const ushort_t* __restrict__ Bh,
                                                  const ushort_t* __restrict__ Bl,
                                                  const float* __restrict__ bias_l,
                                                  const float* __restrict__ bias_r,
                                                  float* __restrict__ C_l,
                                                  float* __restrict__ C_r,
                                                  int M, int K, int NcT, int Nsplit) {
  __shared__ ushort_t sAh[2][128 * 40];   // padded: row stride 40 bf16 (80 B)
  __shared__ ushort_t sAl[2][128 * 40];
  __shared__ ushort_t sBh[2][128 * 32];   // [sub_k][col] packed: elem (sub*128+col)*8
  __shared__ ushort_t sBl[2][128 * 32];

  // swizzled 1-D grid decode: co-locate all P col-panels of a row-panel on one XCD
  const int P = NcT >> 7;                  // 2 (enc) or 4 (layers)
  const int plog = (P == 2) ? 1 : 2;
  const int id = blockIdx.x;
  const int xcd = id & 7;
  const int kk = id >> 3;
  const int cpan = kk & (P - 1);
  const int Rhi = kk >> plog;
  const int R = (Rhi << 3) + xcd;          // row panel
  const int MBp = (M + 127) >> 7;
  if (R >= MBp) return;                    // idle pad block (whole block exits)

  const int tid = threadIdx.x;
  const int lane = tid & 63;
  const int w = tid >> 6;
  const int wm = w >> 1, wn = w & 1;  // 2x2 wave grid: wave tile 64x64 at (wm*64, wn*64)
  const int bm = R * 128;
  const int bn = cpan * 128;
  const int r = lane & 15, q = lane >> 4;

  floatx4 acc[4][4];
  #pragma unroll
  for (int i = 0; i < 4; ++i)
    #pragma unroll
    for (int j = 0; j < 4; ++j) acc[i][j] = (floatx4)(0.0f);

  // A staging: thread -> row=tid>>1 (128 rows), chunk=tid&1 (16 floats each)
  const int arow = tid >> 1, achunk = tid & 1;
  int ag = bm + arow; if (ag >= M) ag = M - 1;   // clamp; garbage rows never stored
  const float* aptr = A + (size_t)ag * K + achunk * 16;
  const int awoff = arow * 40 + achunk * 16;

  // B staging: entries e0=tid, e1=tid+256 of 512 x 16B per half
  const int e0 = tid, e1 = tid + 256;
  const size_t b0base = ((size_t)(e0 >> 7) * NcT + bn + (e0 & 127)) * 8;
  const size_t b1base = ((size_t)(e1 >> 7) * NcT + bn + (e1 & 127)) * 8;

  const int nt = K >> 5;   // K / 32

  // ---- prologue: fill buffer 0 with tile 0 ----
  {
    gload_lds16(Bh + b0base, &sBh[0][e0 * 8]);
    gload_lds16(Bh + b1base, &sBh[0][e1 * 8]);
    gload_lds16(Bl + b0base, &sBl[0][e0 * 8]);
    gload_lds16(Bl + b1base, &sBl[0][e1 * 8]);
    float va[16];
    *(float4*)&va[0]  = *(const float4*)(aptr + 0);
    *(float4*)&va[4]  = *(const float4*)(aptr + 4);
    *(float4*)&va[8]  = *(const float4*)(aptr + 8);
    *(float4*)&va[12] = *(const float4*)(aptr + 12);
    split_store16(va, sAh[0], sAl[0], awoff);
  }
  __syncthreads();

  int cur = 0;
  for (int t = 0; t < nt; ++t) {
    const bool has_next = (t + 1 < nt);
    float va[16];
    if (has_next) {
      const int k0n = (t + 1) << 5;
      // issue next A loads to regs (HBM latency hides under MFMA below)
      *(float4*)&va[0]  = *(const float4*)(aptr + k0n + 0);
      *(float4*)&va[4]  = *(const float4*)(aptr + k0n + 4);
      *(float4*)&va[8]  = *(const float4*)(aptr + k0n + 8);
      *(float4*)&va[12] = *(const float4*)(aptr + k0n + 12);
      // issue next B async global->LDS into buf^1
      size_t kadd = (size_t)(k0n >> 3) * NcT * 8;
      gload_lds16(Bh + b0base + kadd, &sBh[cur ^ 1][e0 * 8]);
      gload_lds16(Bh + b1base + kadd, &sBh[cur ^ 1][e1 * 8]);
      gload_lds16(Bl + b0base + kadd, &sBl[cur ^ 1][e0 * 8]);
      gload_lds16(Bl + b1base + kadd, &sBl[cur ^ 1][e1 * 8]);
    }

    // compute current tile from buf[cur]
    short8 ah[4], al[4];
    #pragma unroll
    for (int i = 0; i < 4; ++i) {
      int off = (wm * 64 + i * 16 + r) * 40 + q * 8;
      ah[i] = *(const short8*)&sAh[cur][off];
      al[i] = *(const short8*)&sAl[cur][off];
    }
    #pragma unroll
    for (int j = 0; j < 4; ++j) {
      int off = (q * 128 + wn * 64 + j * 16 + r) * 8;
      short8 bh = *(const short8*)&sBh[cur][off];
      short8 bl = *(const short8*)&sBl[cur][off];
      #pragma unroll
      for (int i = 0; i < 4; ++i) {
        acc[i][j] = __builtin_amdgcn_mfma_f32_16x16x32_bf16(ah[i], bh, acc[i][j], 0, 0, 0);
        acc[i][j] = __builtin_amdgcn_mfma_f32_16x16x32_bf16(ah[i], bl, acc[i][j], 0, 0, 0);
        acc[i][j] = __builtin_amdgcn_mfma_f32_16x16x32_bf16(al[i], bh, acc[i][j], 0, 0, 0);
      }
    }

    // split prefetched A into buf^1 (waits only on this iteration's A loads)
    if (has_next) split_store16(va, sAh[cur ^ 1], sAl[cur ^ 1], awoff);

    // one drain + barrier per tile
    __syncthreads();
    cur ^= 1;
  }

  // epilogue: C/D layout col=lane&15, row=(lane>>4)*4+reg
  #pragma unroll
  for (int j = 0; j < 4; ++j) {
    int cg = bn + wn * 64 + j * 16 + r;
    bool sec = cg >= Nsplit;
    int cc = sec ? cg - Nsplit : cg;
    float bv = sec ? bias_r[cc] : bias_l[cc];
    float* Cb = sec ? C_r : C_l;
    #pragma unroll
    for (int i = 0; i < 4; ++i) {
      int row0 = bm + wm * 64 + i * 16 + q * 4;
      #pragma unroll
      for (int rr = 0; rr < 4; ++rr) {
        int row = row0 + rr;
        if (row < M) Cb[(size_t)row * HID + cc] = acc[i][j][rr] + bv;
      }
    }
  }
}

// ---------------- GATv2 layer: one wave per destination node, 4 nodes/block ----------------
// Round 6 -> 7: the edge loop was a serial dependent-gather chain (random 1KB
// xl row from L3, ~400-600cy, consumed immediately; zero ILP). Software-
// pipeline pairs: gathers for pair k+1 issue BEFORE processing pair k, so two
// 1KB gathers are in flight under ~300cy of VALU processing. If gat is
// latency-bound this is a 30-45% cut; a null means L3-BW-bound (-> cut bytes).
// Also fuses the classifier (preds != nullptr on layer 1): h row is already in
// registers, saving a 51MB re-read + one launch.
__global__ __launch_bounds__(256) void gat_layer(const float* __restrict__ xl,
                                                 const float* __restrict__ xr,
                                                 float* h_inout,
                                                 const float* __restrict__ att,
                                                 const float* __restrict__ bias,
                                                 const int* __restrict__ row_ptr,
                                                 const int* __restrict__ csr_src,
                                                 const int* __restrict__ csr_eid,
                                                 float* __restrict__ logits_ws,
                                                 float* __restrict__ alpha_out,
                                                 const float* __restrict__ clf_W,
                                                 const float* __restrict__ clf_b,
                                                 float* __restrict__ preds) {
  int node = blockIdx.x * 4 + (threadIdx.x >> 6);   // N_NODES % 4 == 0
  int l = threadIdx.x & 63;
  int hgrp = l >> 4;
  int r0 = row_ptr[node];
  int r1 = row_ptr[node + 1];

  float4 xr4 = *(const float4*)(xr + (size_t)node * HID + l * 4);
  float4 at4 = *(const float4*)(att + l * 4);

  float m = -INFINITY;
  float den = 0.f;
  float4 acc = make_float4(0.f, 0.f, 0.f, 0.f);

  auto process = [&](const float4& v, int j) {
    float t0 = v.x + xr4.x; t0 = (t0 > 0.f) ? t0 : NEG_SLOPE * t0;
    float t1 = v.y + xr4.y; t1 = (t1 > 0.f) ? t1 : NEG_SLOPE * t1;
    float t2 = v.z + xr4.z; t2 = (t2 > 0.f) ? t2 : NEG_SLOPE * t2;
    float t3 = v.w + xr4.w; t3 = (t3 > 0.f) ? t3 : NEG_SLOPE * t3;
    float p = t0 * at4.x + t1 * at4.y + t2 * at4.z + t3 * at4.w;
    p += __shfl_xor(p, 1);
    p += __shfl_xor(p, 2);
    p += __shfl_xor(p, 4);
    p += __shfl_xor(p, 8);
    if ((l & 15) == 0) logits_ws[(size_t)j * NHEAD + hgrp] = p;
    float m_new = fmaxf(m, p);
    float scale = __expf(m - m_new);
    float wgt = __expf(p - m_new);
    den = den * scale + wgt;
    acc.x = acc.x * scale + wgt * v.x;
    acc.y = acc.y * scale + wgt * v.y;
    acc.z = acc.z * scale + wgt * v.z;
    acc.w = acc.w * scale + wgt * v.w;
    m = m_new;
  };

  // software-pipelined pairs (degree >= 1 guaranteed by self-loops)
  float4 v0, v1;
  {
    int s0 = csr_src[r0];
    int s1 = (r0 + 1 < r1) ? csr_src[r0 + 1] : s0;
    v0 = *(const float4*)(xl + (size_t)s0 * HID + l * 4);
    v1 = *(const float4*)(xl + (size_t)s1 * HID + l * 4);
  }
  for (int j = r0; j < r1; j += 2) {
    float4 w0 = v0, w1 = v1;
    int jn = j + 2;
    if (jn < r1) {
      int t0 = csr_src[jn];
      int t1 = (jn + 1 < r1) ? csr_src[jn + 1] : t0;
      v0 = *(const float4*)(xl + (size_t)t0 * HID + l * 4);
      v1 = *(const float4*)(xl + (size_t)t1 * HID + l * 4);
    }
    process(w0, j);
    if (j + 1 < r1) process(w1, j + 1);
  }
  float inv_den = 1.f / (den + 1e-16f);

  float4 b4 = *(const float4*)(bias + l * 4);
  float4 h4 = *(const float4*)(h_inout + (size_t)node * HID + l * 4);
  float o0 = acc.x * inv_den + b4.x + h4.x;
  float o1 = acc.y * inv_den + b4.y + h4.y;
  float o2 = acc.z * inv_den + b4.z + h4.z;
  float o3 = acc.w * inv_den + b4.w + h4.w;
  o0 = (o0 > 0.f) ? o0 : (__expf(o0) - 1.f);
  o1 = (o1 > 0.f) ? o1 : (__expf(o1) - 1.f);
  o2 = (o2 > 0.f) ? o2 : (__expf(o2) - 1.f);
  o3 = (o3 > 0.f) ? o3 : (__expf(o3) - 1.f);
  *(float4*)(h_inout + (size_t)node * HID + l * 4) = make_float4(o0, o1, o2, o3);

  // fused classifier (layer 1 only): h row already in registers
  if (preds != nullptr) {
    float4 cw = *(const float4*)(clf_W + l * 4);
    float s = o0 * cw.x + o1 * cw.y + o2 * cw.z + o3 * cw.w;
    s += __shfl_xor(s, 1);
    s += __shfl_xor(s, 2);
    s += __shfl_xor(s, 4);
    s += __shfl_xor(s, 8);
    s += __shfl_xor(s, 16);
    s += __shfl_xor(s, 32);
    if (l == 0) preds[node] = s + clf_b[0];
  }

  float mh = __shfl(m, (l & 3) * 16);
  float dh = __shfl(den, (l & 3) * 16);
  float invd = 1.f / (dh + 1e-16f);
  for (int j = r0 + (l >> 2); j < r1; j += 16) {
    float lg = logits_ws[(size_t)j * NHEAD + (l & 3)];
    alpha_out[(size_t)csr_eid[j] * NHEAD + (l & 3)] = __expf(lg - mh) * invd;
  }
}

// ---------------- launcher ----------------
static inline char* carve(char*& p, size_t bytes) {
  char* ret = p;
  p += (bytes + 255) & ~(size_t)255;
  return ret;
}

extern "C" void kernel_launch(void* const* d_in, const int* in_sizes, int n_in,
                              void* d_out, int out_size, void* d_ws, size_t ws_size,
                              hipStream_t stream) {
  const float* x     = (const float*)d_in[0];
  const int*   ei    = (const int*)d_in[1];
  const float* enc_W = (const float*)d_in[2];
  const float* enc_b = (const float*)d_in[3];
  const float* Wl0   = (const float*)d_in[4];
  const float* bl0   = (const float*)d_in[5];
  const float* Wr0   = (const float*)d_in[6];
  const float* br0   = (const float*)d_in[7];
  const float* att0  = (const float*)d_in[8];
  const float* bias0 = (const float*)d_in[9];
  const float* Wl1   = (const float*)d_in[10];
  const float* bl1   = (const float*)d_in[11];
  const float* Wr1   = (const float*)d_in[12];
  const float* br1   = (const float*)d_in[13];
  const float* att1  = (const float*)d_in[14];
  const float* bias1 = (const float*)d_in[15];
  const float* clf_W = (const float*)d_in[16];
  const float* clf_b = (const float*)d_in[17];

  float* preds  = (float*)d_out;
  float* alpha0 = preds + N_NODES;
  float* alpha1 = alpha0 + (size_t)EP * NHEAD;

  char* p = (char*)d_ws;
  float* h      = (float*)carve(p, (size_t)N_NODES * HID * 4);
  float* xl     = (float*)carve(p, (size_t)N_NODES * HID * 4);
  float* xr     = (float*)carve(p, (size_t)N_NODES * HID * 4);
  float* logits = (float*)carve(p, (size_t)EP * NHEAD * 4);
  int* row_ptr  = (int*)carve(p, (size_t)(N_NODES + 1) * 4);
  int* cursor   = (int*)carve(p, (size_t)N_NODES * 4);
  int* csr_src  = (int*)carve(p, (size_t)EP * 4);
  int* csr_eid  = (int*)carve(p, (size_t)EP * 4);
  ushort_t* encPh = (ushort_t*)carve(p, (size_t)IN_DIM * HID * 2);
  ushort_t* encPl = (ushort_t*)carve(p, (size_t)IN_DIM * HID * 2);
  ushort_t* P0h   = (ushort_t*)carve(p, (size_t)HID * 512 * 2);
  ushort_t* P0l   = (ushort_t*)carve(p, (size_t)HID * 512 * 2);
  ushort_t* P1h   = (ushort_t*)carve(p, (size_t)HID * 512 * 2);
  ushort_t* P1l   = (ushort_t*)carve(p, (size_t)HID * 512 * 2);

  // --- CSR build ---
  hipMemsetAsync(cursor, 0, N_NODES * sizeof(int), stream);
  int eb = 256, eg = (EP + eb - 1) / eb;
  hist_kernel<<<eg, eb, 0, stream>>>(ei, cursor);
  scan_kernel<<<1, 1024, 0, stream>>>(cursor, row_ptr);
  scatter_kernel<<<eg, eb, 0, stream>>>(ei, cursor, csr_src, csr_eid);

  // --- weight preprocessing: single fused split kernel ---
  {
    const int total = ENC_ELEMS + 4 * LYR_ELEMS;   // 589824
    wsplit_all<<<(total + 255) / 256, 256, 0, stream>>>(enc_W, Wl0, Wr0, Wl1, Wr1,
                                                        encPh, encPl, P0h, P0l, P1h, P1l);
  }

  const int MB = (N_NODES + 127) / 128;      // 391 row-panels
  const int R8 = (MB + 7) / 8;               // 49
  dim3 bGemm(256);

  // swizzled 1-D grids: 8 XCD slots x P col-panels x R8 row-groups
  // encoder: h = x @ enc_W + enc_b   (NcT=256 -> P=2)
  gemm128<<<dim3(8 * 2 * R8), bGemm, 0, stream>>>(x, encPh, encPl, enc_b, enc_b, h, h,
                                                  N_NODES, IN_DIM, HID, HID);

  // layer 0: fused xl|xr = h @ [Wl0|Wr0]   (NcT=512 -> P=4)
  gemm128<<<dim3(8 * 4 * R8), bGemm, 0, stream>>>(h, P0h, P0l, bl0, br0, xl, xr,
                                                  N_NODES, HID, 512, HID);
  gat_layer<<<N_NODES / 4, 256, 0, stream>>>(xl, xr, h, att0, bias0, row_ptr, csr_src,
                                             csr_eid, logits, alpha0, nullptr, nullptr, nullptr);

  // layer 1 (+ fused classifier)
  gemm128<<<dim3(8 * 4 * R8), bGemm, 0, stream>>>(h, P1h, P1l, bl1, br1, xl, xr,
                                                  N_NODES, HID, 512, HID);
  gat_layer<<<N_NODES / 4, 256, 0, stream>>>(xl, xr, h, att1, bias1, row_ptr, csr_src,
                                             csr_eid, logits, alpha1, clf_W, clf_b, preds);
}